// Round 9
// baseline (323.536 us; speedup 1.0000x reference)
//
#include <hip/hip_runtime.h>

typedef __attribute__((ext_vector_type(8))) __bf16 bf16x8;
typedef __attribute__((ext_vector_type(8))) unsigned short u16x8;
typedef __attribute__((ext_vector_type(4))) unsigned short u16x4;
typedef __attribute__((ext_vector_type(4))) float f32x4;

__device__ __forceinline__ f32x4 mfma16(bf16x8 a, bf16x8 b, f32x4 c) {
  return __builtin_amdgcn_mfma_f32_16x16x32_bf16(a, b, c, 0, 0, 0);
}

__device__ __forceinline__ bf16x8 cvt8(f32x4 a, f32x4 b) {
  bf16x8 r;
  r[0] = (__bf16)a[0]; r[1] = (__bf16)a[1]; r[2] = (__bf16)a[2]; r[3] = (__bf16)a[3];
  r[4] = (__bf16)b[0]; r[5] = (__bf16)b[1]; r[6] = (__bf16)b[2]; r[7] = (__bf16)b[3];
  return r;
}

__device__ __forceinline__ unsigned short bf1(float f) {
  return __builtin_bit_cast(unsigned short, (__bf16)f);
}

__device__ __forceinline__ bf16x8 ld_frag(const unsigned short* p) {
  return __builtin_bit_cast(bf16x8, *(const u16x8*)p);
}

// ---------------------------------------------------------------------------
// kprep — identical to R8.
// ---------------------------------------------------------------------------
__global__ __launch_bounds__(256) void kprep(const float* __restrict__ Bw,
                                             const float* __restrict__ Cw,
                                             const float* __restrict__ Al,
                                             const float* __restrict__ Ah,
                                             const float* __restrict__ Dv,
                                             unsigned short* __restrict__ BwF,
                                             unsigned short* __restrict__ CwF,
                                             unsigned short* __restrict__ akbF,
                                             float* __restrict__ dflag,
                                             float* __restrict__ spec,
                                             float* __restrict__ norm_out) {
  const int bid = blockIdx.x, tid = threadIdx.x;
  if (bid < 32) {
    int g = bid * 256 + tid;
    int kstep = g >> 8, nt = (g >> 6) & 3, ln = g & 63;
    int n = nt * 16 + (ln & 15);
    int k = kstep * 32 + (ln >> 4) * 8;
    f32x4 a = *(const f32x4*)&Bw[(size_t)n * 1024 + k];
    f32x4 b = *(const f32x4*)&Bw[(size_t)n * 1024 + k + 4];
    *(u16x8*)&BwF[(size_t)g * 8] = __builtin_bit_cast(u16x8, cvt8(a, b));
    return;
  }
  if (bid < 64) {
    int g = (bid - 32) * 256 + tid;
    int dt = g >> 7, kk = (g >> 6) & 1, ln = g & 63;
    int d = dt * 16 + (ln & 15);
    int n = kk * 32 + (ln >> 4) * 8;
    f32x4 a = *(const f32x4*)&Cw[(size_t)d * 64 + n];
    f32x4 b = *(const f32x4*)&Cw[(size_t)d * 64 + n + 4];
    *(u16x8*)&CwF[(size_t)g * 8] = __builtin_bit_cast(u16x8, cvt8(a, b));
    return;
  }
  __shared__ float A[4][64][68];
  __shared__ float AT[64][68];
  __shared__ float Alo[64][36];
  __shared__ float Ahi[32][68];
  __shared__ float vv[64], ww[64];
  const int lane = tid & 63, wq = tid >> 6;
  for (int f = tid; f < 512; f += 256) {
    int r = f >> 3, c = (f & 7) << 2;
    *(f32x4*)&Alo[r][c] = *(const f32x4*)&Al[r * 32 + c];
  }
  for (int f = tid; f < 512; f += 256) {
    int r = f >> 4, c = (f & 15) << 2;
    *(f32x4*)&Ahi[r][c] = *(const f32x4*)&Ah[r * 64 + c];
  }
  if (tid == 0) *norm_out = 0.0f;
  __syncthreads();
  {
    float ar[32];
#pragma unroll
    for (int r = 0; r < 32; r++) ar[r] = Alo[lane][r];
#pragma unroll
    for (int m4 = 0; m4 < 4; m4++) {
      f32x4 s = {0.f, 0.f, 0.f, 0.f};
#pragma unroll
      for (int r = 0; r < 32; r++)
        s += ar[r] * *(const f32x4*)&Ahi[r][wq * 16 + m4 * 4];
      *(f32x4*)&A[0][lane][wq * 16 + m4 * 4] = s;
    }
  }
  __syncthreads();
  for (int f = tid; f < 4096; f += 256) {
    int r = f >> 6, c = f & 63;
    AT[c][r] = A[0][r][c];
  }
  for (int p = 1; p < 4; p++) {
    f32x4 s[4];
#pragma unroll
    for (int m4 = 0; m4 < 4; m4++) s[m4] = f32x4{0.f, 0.f, 0.f, 0.f};
#pragma unroll
    for (int kc = 0; kc < 4; kc++) {
      float ar[16];
#pragma unroll
      for (int r = 0; r < 16; r++) ar[r] = A[p - 1][lane][kc * 16 + r];
#pragma unroll
      for (int r = 0; r < 16; r++)
#pragma unroll
        for (int m4 = 0; m4 < 4; m4++)
          s[m4] += ar[r] * *(const f32x4*)&A[0][kc * 16 + r][wq * 16 + m4 * 4];
    }
#pragma unroll
    for (int m4 = 0; m4 < 4; m4++)
      *(f32x4*)&A[p][lane][wq * 16 + m4 * 4] = s[m4];
    __syncthreads();
  }
#pragma unroll
  for (int i = 0; i < 8; i++) {
    int e = tid + 256 * i;
    int kp = e >> 9, kk = (e >> 8) & 1, nt = (e >> 6) & 3, ln = e & 63;
    int n = nt * 16 + (ln & 15);
    int mc = kk * 32 + (ln >> 4) * 8;
    f32x4 a = *(const f32x4*)&A[kp][n][mc];
    f32x4 b = *(const f32x4*)&A[kp][n][mc + 4];
    *(u16x8*)&akbF[(size_t)e * 8] = __builtin_bit_cast(u16x8, cvt8(a, b));
  }
  if (wq == 0) {
    float v = 1.0f + 0.001f * (float)lane;
    for (int it = 0; it < 8; it++) {
      vv[lane] = v;
      float w0 = 0.f, w1 = 0.f, w2 = 0.f, w3 = 0.f;
#pragma unroll
      for (int m = 0; m < 64; m += 4) {
        w0 += AT[m + 0][lane] * vv[m + 0];
        w1 += AT[m + 1][lane] * vv[m + 1];
        w2 += AT[m + 2][lane] * vv[m + 2];
        w3 += AT[m + 3][lane] * vv[m + 3];
      }
      float w = (w0 + w1) + (w2 + w3);
      ww[lane] = w;
      float z0 = 0.f, z1 = 0.f, z2 = 0.f, z3 = 0.f;
#pragma unroll
      for (int m = 0; m < 64; m += 4) {
        z0 += A[0][m + 0][lane] * ww[m + 0];
        z1 += A[0][m + 1][lane] * ww[m + 1];
        z2 += A[0][m + 2][lane] * ww[m + 2];
        z3 += A[0][m + 3][lane] * ww[m + 3];
      }
      float z = (z0 + z1) + (z2 + z3);
      float ss = z * z;
#pragma unroll
      for (int off = 32; off; off >>= 1) ss += __shfl_xor(ss, off, 64);
      v = z * rsqrtf(ss + 1e-38f);
    }
    vv[lane] = v;
    float w0 = 0.f, w1 = 0.f, w2 = 0.f, w3 = 0.f;
#pragma unroll
    for (int m = 0; m < 64; m += 4) {
      w0 += AT[m + 0][lane] * vv[m + 0];
      w1 += AT[m + 1][lane] * vv[m + 1];
      w2 += AT[m + 2][lane] * vv[m + 2];
      w3 += AT[m + 3][lane] * vv[m + 3];
    }
    float w = (w0 + w1) + (w2 + w3);
    float ss = w * w;
#pragma unroll
    for (int off = 32; off; off >>= 1) ss += __shfl_xor(ss, off, 64);
    if (lane == 0) *spec = sqrtf(ss);
  }
  if (wq == 1) {
    float dm = 0.f;
#pragma unroll
    for (int i = 0; i < 16; i++) dm = fmaxf(dm, fabsf(Dv[lane + i * 64]));
#pragma unroll
    for (int off = 32; off; off >>= 1) dm = fmaxf(dm, __shfl_xor(dm, off, 64));
    if (lane == 0) *dflag = dm;
  }
}

// ---------------------------------------------------------------------------
// G1 — identical to R8.
// ---------------------------------------------------------------------------
__global__ __launch_bounds__(512, 4) void g1_gemm(const float* __restrict__ x,
                                                  const unsigned short* __restrict__ BwF,
                                                  const float* __restrict__ Bb,
                                                  const float* __restrict__ rw,
                                                  float* __restrict__ u) {
  __shared__ f32x4 accS[4][4][64];
  const int tid = threadIdx.x, lane = tid & 63, wid = tid >> 6;
  const int rt = wid & 3, kh = wid >> 2;
  const int t0 = blockIdx.x * 64 + rt * 16;
  const int trow = t0 + (lane & 15);
  const int q8 = (lane >> 4) * 8;
  const float* xrow = &x[(size_t)trow * 1024 + kh * 512 + q8];
  f32x4 acc[4];
#pragma unroll
  for (int nt = 0; nt < 4; nt++) acc[nt] = f32x4{0.f, 0.f, 0.f, 0.f};
  const int ksb = kh * 16;
  f32x4 pxa = *(const f32x4*)(xrow);
  f32x4 pxb = *(const f32x4*)(xrow + 4);
  bf16x8 pb[4];
#pragma unroll
  for (int nt = 0; nt < 4; nt++)
    pb[nt] = ld_frag(&BwF[((size_t)(ksb * 4 + nt) * 64 + lane) * 8]);
#pragma unroll
  for (int i = 0; i < 16; i++) {
    f32x4 cxa = pxa, cxb = pxb;
    bf16x8 cb0 = pb[0], cb1 = pb[1], cb2 = pb[2], cb3 = pb[3];
    if (i < 15) {
      pxa = *(const f32x4*)(xrow + (i + 1) * 32);
      pxb = *(const f32x4*)(xrow + (i + 1) * 32 + 4);
#pragma unroll
      for (int nt = 0; nt < 4; nt++)
        pb[nt] = ld_frag(&BwF[((size_t)((ksb + i + 1) * 4 + nt) * 64 + lane) * 8]);
    }
    bf16x8 bop = cvt8(cxa, cxb);
    acc[0] = mfma16(cb0, bop, acc[0]);
    acc[1] = mfma16(cb1, bop, acc[1]);
    acc[2] = mfma16(cb2, bop, acc[2]);
    acc[3] = mfma16(cb3, bop, acc[3]);
  }
  if (kh == 1) {
#pragma unroll
    for (int nt = 0; nt < 4; nt++) accS[rt][nt][lane] = acc[nt];
  }
  __syncthreads();
  if (kh == 0) {
    const float rwt = rw[trow];
#pragma unroll
    for (int nt = 0; nt < 4; nt++) {
      acc[nt] += accS[rt][nt][lane];
      int n0 = nt * 16 + (lane >> 4) * 4;
      f32x4 bb = *(const f32x4*)&Bb[n0];
      f32x4 o;
#pragma unroll
      for (int j = 0; j < 4; j++) o[j] = (acc[nt][j] + bb[j]) * rwt;
      *(f32x4*)&u[(size_t)trow * 64 + n0] = o;
    }
  }
}

// ---------------------------------------------------------------------------
// K2 — identical to R8.
// ---------------------------------------------------------------------------
__global__ __launch_bounds__(256) void k2_hs(const float* __restrict__ u,
                                             const unsigned short* __restrict__ akbF,
                                             unsigned short* __restrict__ hsbF,
                                             float* __restrict__ norm_out) {
  __shared__ unsigned short hsT[4][16][72];
  const int tid = threadIdx.x, lane = tid & 63, wid = tid >> 6;
  const int tt = blockIdx.x * 4 + wid;
  const int t0 = tt * 16;
  const int bst = t0 & ~4095;
  const int l15 = lane & 15;
  const int q8 = (lane >> 4) * 8;
  const int n4 = (lane >> 4) * 4;
  const int tcol = t0 + l15;
  f32x4 h[4];
#pragma unroll
  for (int nt = 0; nt < 4; nt++) h[nt] = f32x4{0.f, 0.f, 0.f, 0.f};
#pragma unroll
  for (int kp = 1; kp <= 4; kp++) {
    const bool ok = (tcol - kp) >= bst;
    const float* up = &u[(size_t)(tcol - kp) * 64];
#pragma unroll
    for (int kk = 0; kk < 2; kk++) {
      f32x4 xa = {0.f, 0.f, 0.f, 0.f}, xb = {0.f, 0.f, 0.f, 0.f};
      if (ok) {
        xa = *(const f32x4*)(up + kk * 32 + q8);
        xb = *(const f32x4*)(up + kk * 32 + q8 + 4);
      }
      bf16x8 b = cvt8(xa, xb);
#pragma unroll
      for (int nt = 0; nt < 4; nt++) {
        bf16x8 a = ld_frag(&akbF[(size_t)((((kp - 1) * 2 + kk) * 4 + nt) * 64 + lane) * 8]);
        h[nt] = mfma16(a, b, h[nt]);
      }
    }
  }
#pragma unroll
  for (int nt = 0; nt < 4; nt++) {
    f32x4 uid = *(const f32x4*)&u[(size_t)tcol * 64 + nt * 16 + n4];
    h[nt] += uid;
  }
  const bool bend = ((t0 + 15) & 4095) == 4095;
  if (bend) {
    float ss = 0.f;
    if (l15 == 15) {
#pragma unroll
      for (int nt = 0; nt < 4; nt++)
#pragma unroll
        for (int j = 0; j < 4; j++) ss += h[nt][j] * h[nt][j];
    }
    ss += __shfl_xor(ss, 16, 64);
    ss += __shfl_xor(ss, 32, 64);
    if (lane == 15) atomicAdd(norm_out, sqrtf(ss) * 0.125f);
  }
#pragma unroll
  for (int nt = 0; nt < 4; nt++) {
    u16x4 pk;
#pragma unroll
    for (int j = 0; j < 4; j++) pk[j] = bf1(h[nt][j]);
    *(u16x4*)&hsT[wid][l15][nt * 16 + n4] = pk;
  }
#pragma unroll
  for (int kk = 0; kk < 2; kk++) {
    bf16x8 hf = ld_frag(&hsT[wid][l15][kk * 32 + q8]);
    *(u16x8*)&hsbF[((size_t)(tt * 2 + kk) * 64 + lane) * 8] =
        __builtin_bit_cast(u16x8, hf);
  }
}

// ---------------------------------------------------------------------------
// G2 (x REPS this round — MEASUREMENT TARGET; body identical to R8).
// ---------------------------------------------------------------------------
__global__ __launch_bounds__(256, 4) void g2_gemm(const unsigned short* __restrict__ hsbF,
                                                  const unsigned short* __restrict__ CwF,
                                                  const float* __restrict__ Cb,
                                                  const float* __restrict__ Dv,
                                                  const float* __restrict__ x,
                                                  const float* __restrict__ dflag,
                                                  float* __restrict__ out,
                                                  int reps) {
  const int tid = threadIdx.x, lane = tid & 63, wid = tid >> 6;
  const int idx = blockIdx.x * 4 + wid;
  const int dc = idx & 15, tg = idx >> 4;
  const int d0 = dc * 64;
  const int l15 = lane & 15;
  const int n4 = (lane >> 4) * 4;
  const bool hasD = (*dflag != 0.0f);
  for (int rep = 0; rep < reps; rep++) {
    bf16x8 cw[4][2];
#pragma unroll
    for (int dt = 0; dt < 4; dt++)
#pragma unroll
      for (int kk = 0; kk < 2; kk++)
        cw[dt][kk] = ld_frag(&CwF[(size_t)((((d0 >> 4) + dt) * 2 + kk) * 64 + lane) * 8]);
    f32x4 cb[4], dd[4];
#pragma unroll
    for (int dt = 0; dt < 4; dt++) {
      cb[dt] = *(const f32x4*)&Cb[d0 + dt * 16 + n4];
      dd[dt] = *(const f32x4*)&Dv[d0 + dt * 16 + n4];
    }
#pragma unroll
    for (int s = 0; s < 4; s++) {
      const int tt = tg * 4 + s;
      bf16x8 hf0 = ld_frag(&hsbF[((size_t)(tt * 2 + 0) * 64 + lane) * 8]);
      bf16x8 hf1 = ld_frag(&hsbF[((size_t)(tt * 2 + 1) * 64 + lane) * 8]);
      f32x4 o[4];
#pragma unroll
      for (int dt = 0; dt < 4; dt++) o[dt] = f32x4{0.f, 0.f, 0.f, 0.f};
#pragma unroll
      for (int dt = 0; dt < 4; dt++) {
        o[dt] = mfma16(cw[dt][0], hf0, o[dt]);
        o[dt] = mfma16(cw[dt][1], hf1, o[dt]);
      }
      const int trow = tt * 16 + l15;
      const size_t xrow = (size_t)trow * 1024;
#pragma unroll
      for (int dt = 0; dt < 4; dt++) {
        int db = d0 + dt * 16 + n4;
        f32x4 v = o[dt] + cb[dt];
        if (hasD) {
          f32x4 xv = *(const f32x4*)&x[xrow + db];
          v += dd[dt] * xv;
        }
        *(f32x4*)&out[xrow + db] = v;
      }
    }
  }
}

extern "C" void kernel_launch(void* const* d_in, const int* in_sizes, int n_in,
                              void* d_out, int out_size, void* d_ws, size_t ws_size,
                              hipStream_t stream) {
  const float* x  = (const float*)d_in[0];
  const float* rw = (const float*)d_in[1];
  const float* Al = (const float*)d_in[2];
  const float* Ah = (const float*)d_in[3];
  const float* Bw = (const float*)d_in[4];
  const float* Bb = (const float*)d_in[5];
  const float* Cw = (const float*)d_in[6];
  const float* Cb = (const float*)d_in[7];
  const float* Dv = (const float*)d_in[8];
  float* out = (float*)d_out;

  char* ws = (char*)d_ws;
  unsigned short* akbF  = (unsigned short*)(ws);                      // 32 KiB
  float*          dflag = (float*)(ws + 32768);                       // 4 B
  unsigned short* BwF   = (unsigned short*)(ws + 65536);              // 128 KiB
  unsigned short* CwF   = (unsigned short*)(ws + 196608);             // 128 KiB
  float*          u     = (float*)(ws + 327680);                      // 8 MiB
  unsigned short* hsbF  = (unsigned short*)(ws + 327680 + 8388608);   // 4 MiB

  float* norm_out = out + (out_size - 2);
  float* spec_out = out + (out_size - 1);

  // MEASUREMENT ROUND 2: isolate g2 (reps=10). kprep/g1/k2 single-pass,
  // byte-identical to R8. Official dur is sacrificial this round.
  kprep<<<dim3(65), dim3(256), 0, stream>>>(Bw, Cw, Al, Ah, Dv, BwF, CwF, akbF,
                                            dflag, spec_out, norm_out);
  g1_gemm<<<dim3(512), dim3(512), 0, stream>>>(x, BwF, Bb, rw, u);
  k2_hs<<<dim3(512), dim3(256), 0, stream>>>(u, akbF, hsbF, norm_out);
  g2_gemm<<<dim3(2048), dim3(256), 0, stream>>>(hsbF, CwF, Cb, Dv, x, dflag, out, 10);
}

// Round 10
// 120.751 us; speedup vs baseline: 2.6794x; 2.6794x over previous
//
#include <hip/hip_runtime.h>

typedef __attribute__((ext_vector_type(8))) __bf16 bf16x8;
typedef __attribute__((ext_vector_type(8))) unsigned short u16x8;
typedef __attribute__((ext_vector_type(4))) unsigned short u16x4;
typedef __attribute__((ext_vector_type(4))) float f32x4;

__device__ __forceinline__ f32x4 mfma16(bf16x8 a, bf16x8 b, f32x4 c) {
  return __builtin_amdgcn_mfma_f32_16x16x32_bf16(a, b, c, 0, 0, 0);
}

__device__ __forceinline__ bf16x8 cvt8(f32x4 a, f32x4 b) {
  bf16x8 r;
  r[0] = (__bf16)a[0]; r[1] = (__bf16)a[1]; r[2] = (__bf16)a[2]; r[3] = (__bf16)a[3];
  r[4] = (__bf16)b[0]; r[5] = (__bf16)b[1]; r[6] = (__bf16)b[2]; r[7] = (__bf16)b[3];
  return r;
}

__device__ __forceinline__ unsigned short bf1(float f) {
  return __builtin_bit_cast(unsigned short, (__bf16)f);
}

__device__ __forceinline__ bf16x8 ld_frag(const unsigned short* p) {
  return __builtin_bit_cast(bf16x8, *(const u16x8*)p);
}

// ---------------------------------------------------------------------------
// kprep — identical to R8.
// ---------------------------------------------------------------------------
__global__ __launch_bounds__(256) void kprep(const float* __restrict__ Bw,
                                             const float* __restrict__ Cw,
                                             const float* __restrict__ Al,
                                             const float* __restrict__ Ah,
                                             const float* __restrict__ Dv,
                                             unsigned short* __restrict__ BwF,
                                             unsigned short* __restrict__ CwF,
                                             unsigned short* __restrict__ akbF,
                                             float* __restrict__ dflag,
                                             float* __restrict__ spec,
                                             float* __restrict__ norm_out) {
  const int bid = blockIdx.x, tid = threadIdx.x;
  if (bid < 32) {
    int g = bid * 256 + tid;
    int kstep = g >> 8, nt = (g >> 6) & 3, ln = g & 63;
    int n = nt * 16 + (ln & 15);
    int k = kstep * 32 + (ln >> 4) * 8;
    f32x4 a = *(const f32x4*)&Bw[(size_t)n * 1024 + k];
    f32x4 b = *(const f32x4*)&Bw[(size_t)n * 1024 + k + 4];
    *(u16x8*)&BwF[(size_t)g * 8] = __builtin_bit_cast(u16x8, cvt8(a, b));
    return;
  }
  if (bid < 64) {
    int g = (bid - 32) * 256 + tid;
    int dt = g >> 7, kk = (g >> 6) & 1, ln = g & 63;
    int d = dt * 16 + (ln & 15);
    int n = kk * 32 + (ln >> 4) * 8;
    f32x4 a = *(const f32x4*)&Cw[(size_t)d * 64 + n];
    f32x4 b = *(const f32x4*)&Cw[(size_t)d * 64 + n + 4];
    *(u16x8*)&CwF[(size_t)g * 8] = __builtin_bit_cast(u16x8, cvt8(a, b));
    return;
  }
  __shared__ float A[4][64][68];
  __shared__ float AT[64][68];
  __shared__ float Alo[64][36];
  __shared__ float Ahi[32][68];
  __shared__ float vv[64], ww[64];
  const int lane = tid & 63, wq = tid >> 6;
  for (int f = tid; f < 512; f += 256) {
    int r = f >> 3, c = (f & 7) << 2;
    *(f32x4*)&Alo[r][c] = *(const f32x4*)&Al[r * 32 + c];
  }
  for (int f = tid; f < 512; f += 256) {
    int r = f >> 4, c = (f & 15) << 2;
    *(f32x4*)&Ahi[r][c] = *(const f32x4*)&Ah[r * 64 + c];
  }
  if (tid == 0) *norm_out = 0.0f;
  __syncthreads();
  {
    float ar[32];
#pragma unroll
    for (int r = 0; r < 32; r++) ar[r] = Alo[lane][r];
#pragma unroll
    for (int m4 = 0; m4 < 4; m4++) {
      f32x4 s = {0.f, 0.f, 0.f, 0.f};
#pragma unroll
      for (int r = 0; r < 32; r++)
        s += ar[r] * *(const f32x4*)&Ahi[r][wq * 16 + m4 * 4];
      *(f32x4*)&A[0][lane][wq * 16 + m4 * 4] = s;
    }
  }
  __syncthreads();
  for (int f = tid; f < 4096; f += 256) {
    int r = f >> 6, c = f & 63;
    AT[c][r] = A[0][r][c];
  }
  for (int p = 1; p < 4; p++) {
    f32x4 s[4];
#pragma unroll
    for (int m4 = 0; m4 < 4; m4++) s[m4] = f32x4{0.f, 0.f, 0.f, 0.f};
#pragma unroll
    for (int kc = 0; kc < 4; kc++) {
      float ar[16];
#pragma unroll
      for (int r = 0; r < 16; r++) ar[r] = A[p - 1][lane][kc * 16 + r];
#pragma unroll
      for (int r = 0; r < 16; r++)
#pragma unroll
        for (int m4 = 0; m4 < 4; m4++)
          s[m4] += ar[r] * *(const f32x4*)&A[0][kc * 16 + r][wq * 16 + m4 * 4];
    }
#pragma unroll
    for (int m4 = 0; m4 < 4; m4++)
      *(f32x4*)&A[p][lane][wq * 16 + m4 * 4] = s[m4];
    __syncthreads();
  }
#pragma unroll
  for (int i = 0; i < 8; i++) {
    int e = tid + 256 * i;
    int kp = e >> 9, kk = (e >> 8) & 1, nt = (e >> 6) & 3, ln = e & 63;
    int n = nt * 16 + (ln & 15);
    int mc = kk * 32 + (ln >> 4) * 8;
    f32x4 a = *(const f32x4*)&A[kp][n][mc];
    f32x4 b = *(const f32x4*)&A[kp][n][mc + 4];
    *(u16x8*)&akbF[(size_t)e * 8] = __builtin_bit_cast(u16x8, cvt8(a, b));
  }
  if (wq == 0) {
    float v = 1.0f + 0.001f * (float)lane;
    for (int it = 0; it < 8; it++) {
      vv[lane] = v;
      float w0 = 0.f, w1 = 0.f, w2 = 0.f, w3 = 0.f;
#pragma unroll
      for (int m = 0; m < 64; m += 4) {
        w0 += AT[m + 0][lane] * vv[m + 0];
        w1 += AT[m + 1][lane] * vv[m + 1];
        w2 += AT[m + 2][lane] * vv[m + 2];
        w3 += AT[m + 3][lane] * vv[m + 3];
      }
      float w = (w0 + w1) + (w2 + w3);
      ww[lane] = w;
      float z0 = 0.f, z1 = 0.f, z2 = 0.f, z3 = 0.f;
#pragma unroll
      for (int m = 0; m < 64; m += 4) {
        z0 += A[0][m + 0][lane] * ww[m + 0];
        z1 += A[0][m + 1][lane] * ww[m + 1];
        z2 += A[0][m + 2][lane] * ww[m + 2];
        z3 += A[0][m + 3][lane] * ww[m + 3];
      }
      float z = (z0 + z1) + (z2 + z3);
      float ss = z * z;
#pragma unroll
      for (int off = 32; off; off >>= 1) ss += __shfl_xor(ss, off, 64);
      v = z * rsqrtf(ss + 1e-38f);
    }
    vv[lane] = v;
    float w0 = 0.f, w1 = 0.f, w2 = 0.f, w3 = 0.f;
#pragma unroll
    for (int m = 0; m < 64; m += 4) {
      w0 += AT[m + 0][lane] * vv[m + 0];
      w1 += AT[m + 1][lane] * vv[m + 1];
      w2 += AT[m + 2][lane] * vv[m + 2];
      w3 += AT[m + 3][lane] * vv[m + 3];
    }
    float w = (w0 + w1) + (w2 + w3);
    float ss = w * w;
#pragma unroll
    for (int off = 32; off; off >>= 1) ss += __shfl_xor(ss, off, 64);
    if (lane == 0) *spec = sqrtf(ss);
  }
  if (wq == 1) {
    float dm = 0.f;
#pragma unroll
    for (int i = 0; i < 16; i++) dm = fmaxf(dm, fabsf(Dv[lane + i * 64]));
#pragma unroll
    for (int off = 32; off; off >>= 1) dm = fmaxf(dm, __shfl_xor(dm, off, 64));
    if (lane == 0) *dflag = dm;
  }
}

// ---------------------------------------------------------------------------
// G1 (split-K x2, DEEP pipeline): x prefetch depth 4 (~600cy lookahead),
// BwF frag prefetch depth 2 (~300cy, L2). Static buffer rotation (i&3, i&1)
// inside a fully unrolled 16-iter loop — all indices compile-time.
// ---------------------------------------------------------------------------
__global__ __launch_bounds__(512, 4) void g1_gemm(const float* __restrict__ x,
                                                  const unsigned short* __restrict__ BwF,
                                                  const float* __restrict__ Bb,
                                                  const float* __restrict__ rw,
                                                  float* __restrict__ u) {
  __shared__ f32x4 accS[4][4][64];
  const int tid = threadIdx.x, lane = tid & 63, wid = tid >> 6;
  const int rt = wid & 3, kh = wid >> 2;
  const int t0 = blockIdx.x * 64 + rt * 16;
  const int trow = t0 + (lane & 15);
  const int q8 = (lane >> 4) * 8;
  const float* xrow = &x[(size_t)trow * 1024 + kh * 512 + q8];
  // frag (s,nt) lives at bwBase + (s*4+nt)*512 shorts (s = K-step in this half)
  const unsigned short* bwBase = &BwF[((size_t)(kh * 64) * 64 + lane) * 8];
  f32x4 acc[4];
#pragma unroll
  for (int nt = 0; nt < 4; nt++) acc[nt] = f32x4{0.f, 0.f, 0.f, 0.f};
  f32x4 px[4][2];
  bf16x8 pf[2][4];
#pragma unroll
  for (int s = 0; s < 2; s++)
#pragma unroll
    for (int nt = 0; nt < 4; nt++)
      pf[s][nt] = ld_frag(bwBase + (size_t)(s * 4 + nt) * 512);
#pragma unroll
  for (int j = 0; j < 4; j++) {
    px[j][0] = *(const f32x4*)(xrow + j * 32);
    px[j][1] = *(const f32x4*)(xrow + j * 32 + 4);
  }
#pragma unroll
  for (int i = 0; i < 16; i++) {
    bf16x8 bop = cvt8(px[i & 3][0], px[i & 3][1]);
    acc[0] = mfma16(pf[i & 1][0], bop, acc[0]);
    acc[1] = mfma16(pf[i & 1][1], bop, acc[1]);
    acc[2] = mfma16(pf[i & 1][2], bop, acc[2]);
    acc[3] = mfma16(pf[i & 1][3], bop, acc[3]);
    if (i + 2 < 16) {
#pragma unroll
      for (int nt = 0; nt < 4; nt++)
        pf[i & 1][nt] = ld_frag(bwBase + (size_t)((i + 2) * 4 + nt) * 512);
    }
    if (i + 4 < 16) {
      px[i & 3][0] = *(const f32x4*)(xrow + (i + 4) * 32);
      px[i & 3][1] = *(const f32x4*)(xrow + (i + 4) * 32 + 4);
    }
  }
  if (kh == 1) {
#pragma unroll
    for (int nt = 0; nt < 4; nt++) accS[rt][nt][lane] = acc[nt];
  }
  __syncthreads();
  if (kh == 0) {
    const float rwt = rw[trow];
#pragma unroll
    for (int nt = 0; nt < 4; nt++) {
      acc[nt] += accS[rt][nt][lane];
      int n0 = nt * 16 + (lane >> 4) * 4;
      f32x4 bb = *(const f32x4*)&Bb[n0];
      f32x4 o;
#pragma unroll
      for (int j = 0; j < 4; j++) o[j] = (acc[nt][j] + bb[j]) * rwt;
      *(f32x4*)&u[(size_t)trow * 64 + n0] = o;
    }
  }
}

// ---------------------------------------------------------------------------
// K2 — identical to R8.
// ---------------------------------------------------------------------------
__global__ __launch_bounds__(256) void k2_hs(const float* __restrict__ u,
                                             const unsigned short* __restrict__ akbF,
                                             unsigned short* __restrict__ hsbF,
                                             float* __restrict__ norm_out) {
  __shared__ unsigned short hsT[4][16][72];
  const int tid = threadIdx.x, lane = tid & 63, wid = tid >> 6;
  const int tt = blockIdx.x * 4 + wid;
  const int t0 = tt * 16;
  const int bst = t0 & ~4095;
  const int l15 = lane & 15;
  const int q8 = (lane >> 4) * 8;
  const int n4 = (lane >> 4) * 4;
  const int tcol = t0 + l15;
  f32x4 h[4];
#pragma unroll
  for (int nt = 0; nt < 4; nt++) h[nt] = f32x4{0.f, 0.f, 0.f, 0.f};
#pragma unroll
  for (int kp = 1; kp <= 4; kp++) {
    const bool ok = (tcol - kp) >= bst;
    const float* up = &u[(size_t)(tcol - kp) * 64];
#pragma unroll
    for (int kk = 0; kk < 2; kk++) {
      f32x4 xa = {0.f, 0.f, 0.f, 0.f}, xb = {0.f, 0.f, 0.f, 0.f};
      if (ok) {
        xa = *(const f32x4*)(up + kk * 32 + q8);
        xb = *(const f32x4*)(up + kk * 32 + q8 + 4);
      }
      bf16x8 b = cvt8(xa, xb);
#pragma unroll
      for (int nt = 0; nt < 4; nt++) {
        bf16x8 a = ld_frag(&akbF[(size_t)((((kp - 1) * 2 + kk) * 4 + nt) * 64 + lane) * 8]);
        h[nt] = mfma16(a, b, h[nt]);
      }
    }
  }
#pragma unroll
  for (int nt = 0; nt < 4; nt++) {
    f32x4 uid = *(const f32x4*)&u[(size_t)tcol * 64 + nt * 16 + n4];
    h[nt] += uid;
  }
  const bool bend = ((t0 + 15) & 4095) == 4095;
  if (bend) {
    float ss = 0.f;
    if (l15 == 15) {
#pragma unroll
      for (int nt = 0; nt < 4; nt++)
#pragma unroll
        for (int j = 0; j < 4; j++) ss += h[nt][j] * h[nt][j];
    }
    ss += __shfl_xor(ss, 16, 64);
    ss += __shfl_xor(ss, 32, 64);
    if (lane == 15) atomicAdd(norm_out, sqrtf(ss) * 0.125f);
  }
#pragma unroll
  for (int nt = 0; nt < 4; nt++) {
    u16x4 pk;
#pragma unroll
    for (int j = 0; j < 4; j++) pk[j] = bf1(h[nt][j]);
    *(u16x4*)&hsT[wid][l15][nt * 16 + n4] = pk;
  }
#pragma unroll
  for (int kk = 0; kk < 2; kk++) {
    bf16x8 hf = ld_frag(&hsT[wid][l15][kk * 32 + q8]);
    *(u16x8*)&hsbF[((size_t)(tt * 2 + kk) * 64 + lane) * 8] =
        __builtin_bit_cast(u16x8, hf);
  }
}

// ---------------------------------------------------------------------------
// G2 weight-stationary — identical to R8 (single-pass; reps removed).
// Measured R9: 24.5us single-pass vs 19.5us write floor.
// ---------------------------------------------------------------------------
__global__ __launch_bounds__(256, 4) void g2_gemm(const unsigned short* __restrict__ hsbF,
                                                  const unsigned short* __restrict__ CwF,
                                                  const float* __restrict__ Cb,
                                                  const float* __restrict__ Dv,
                                                  const float* __restrict__ x,
                                                  const float* __restrict__ dflag,
                                                  float* __restrict__ out) {
  const int tid = threadIdx.x, lane = tid & 63, wid = tid >> 6;
  const int idx = blockIdx.x * 4 + wid;
  const int dc = idx & 15, tg = idx >> 4;
  const int d0 = dc * 64;
  const int l15 = lane & 15;
  const int n4 = (lane >> 4) * 4;
  const bool hasD = (*dflag != 0.0f);
  bf16x8 cw[4][2];
#pragma unroll
  for (int dt = 0; dt < 4; dt++)
#pragma unroll
    for (int kk = 0; kk < 2; kk++)
      cw[dt][kk] = ld_frag(&CwF[(size_t)((((d0 >> 4) + dt) * 2 + kk) * 64 + lane) * 8]);
  f32x4 cb[4], dd[4];
#pragma unroll
  for (int dt = 0; dt < 4; dt++) {
    cb[dt] = *(const f32x4*)&Cb[d0 + dt * 16 + n4];
    dd[dt] = *(const f32x4*)&Dv[d0 + dt * 16 + n4];
  }
#pragma unroll
  for (int s = 0; s < 4; s++) {
    const int tt = tg * 4 + s;
    bf16x8 hf0 = ld_frag(&hsbF[((size_t)(tt * 2 + 0) * 64 + lane) * 8]);
    bf16x8 hf1 = ld_frag(&hsbF[((size_t)(tt * 2 + 1) * 64 + lane) * 8]);
    f32x4 o[4];
#pragma unroll
    for (int dt = 0; dt < 4; dt++) o[dt] = f32x4{0.f, 0.f, 0.f, 0.f};
#pragma unroll
    for (int dt = 0; dt < 4; dt++) {
      o[dt] = mfma16(cw[dt][0], hf0, o[dt]);
      o[dt] = mfma16(cw[dt][1], hf1, o[dt]);
    }
    const int trow = tt * 16 + l15;
    const size_t xrow = (size_t)trow * 1024;
#pragma unroll
    for (int dt = 0; dt < 4; dt++) {
      int db = d0 + dt * 16 + n4;
      f32x4 v = o[dt] + cb[dt];
      if (hasD) {
        f32x4 xv = *(const f32x4*)&x[xrow + db];
        v += dd[dt] * xv;
      }
      *(f32x4*)&out[xrow + db] = v;
    }
  }
}

extern "C" void kernel_launch(void* const* d_in, const int* in_sizes, int n_in,
                              void* d_out, int out_size, void* d_ws, size_t ws_size,
                              hipStream_t stream) {
  const float* x  = (const float*)d_in[0];
  const float* rw = (const float*)d_in[1];
  const float* Al = (const float*)d_in[2];
  const float* Ah = (const float*)d_in[3];
  const float* Bw = (const float*)d_in[4];
  const float* Bb = (const float*)d_in[5];
  const float* Cw = (const float*)d_in[6];
  const float* Cb = (const float*)d_in[7];
  const float* Dv = (const float*)d_in[8];
  float* out = (float*)d_out;

  char* ws = (char*)d_ws;
  unsigned short* akbF  = (unsigned short*)(ws);                      // 32 KiB
  float*          dflag = (float*)(ws + 32768);                       // 4 B
  unsigned short* BwF   = (unsigned short*)(ws + 65536);              // 128 KiB
  unsigned short* CwF   = (unsigned short*)(ws + 196608);             // 128 KiB
  float*          u     = (float*)(ws + 327680);                      // 8 MiB
  unsigned short* hsbF  = (unsigned short*)(ws + 327680 + 8388608);   // 4 MiB

  float* norm_out = out + (out_size - 2);
  float* spec_out = out + (out_size - 1);

  kprep<<<dim3(65), dim3(256), 0, stream>>>(Bw, Cw, Al, Ah, Dv, BwF, CwF, akbF,
                                            dflag, spec_out, norm_out);
  g1_gemm<<<dim3(512), dim3(512), 0, stream>>>(x, BwF, Bb, rw, u);
  k2_hs<<<dim3(512), dim3(256), 0, stream>>>(u, akbF, hsbF, norm_out);
  g2_gemm<<<dim3(2048), dim3(256), 0, stream>>>(hsbF, CwF, Cb, Dv, x, dflag, out);
}

// Round 11
// 117.020 us; speedup vs baseline: 2.7648x; 1.0319x over previous
//
#include <hip/hip_runtime.h>

typedef __attribute__((ext_vector_type(8))) __bf16 bf16x8;
typedef __attribute__((ext_vector_type(8))) unsigned short u16x8;
typedef __attribute__((ext_vector_type(4))) unsigned short u16x4;
typedef __attribute__((ext_vector_type(4))) float f32x4;

typedef __attribute__((address_space(1))) unsigned int gu32;
typedef __attribute__((address_space(3))) unsigned int lu32;

__device__ __forceinline__ f32x4 mfma16(bf16x8 a, bf16x8 b, f32x4 c) {
  return __builtin_amdgcn_mfma_f32_16x16x32_bf16(a, b, c, 0, 0, 0);
}

__device__ __forceinline__ bf16x8 cvt8(f32x4 a, f32x4 b) {
  bf16x8 r;
  r[0] = (__bf16)a[0]; r[1] = (__bf16)a[1]; r[2] = (__bf16)a[2]; r[3] = (__bf16)a[3];
  r[4] = (__bf16)b[0]; r[5] = (__bf16)b[1]; r[6] = (__bf16)b[2]; r[7] = (__bf16)b[3];
  return r;
}

__device__ __forceinline__ unsigned short bf1(float f) {
  return __builtin_bit_cast(unsigned short, (__bf16)f);
}

__device__ __forceinline__ bf16x8 ld_frag(const unsigned short* p) {
  return __builtin_bit_cast(bf16x8, *(const u16x8*)p);
}

// ---------------------------------------------------------------------------
// kprep — identical to R8.
// ---------------------------------------------------------------------------
__global__ __launch_bounds__(256) void kprep(const float* __restrict__ Bw,
                                             const float* __restrict__ Cw,
                                             const float* __restrict__ Al,
                                             const float* __restrict__ Ah,
                                             const float* __restrict__ Dv,
                                             unsigned short* __restrict__ BwF,
                                             unsigned short* __restrict__ CwF,
                                             unsigned short* __restrict__ akbF,
                                             float* __restrict__ dflag,
                                             float* __restrict__ spec,
                                             float* __restrict__ norm_out) {
  const int bid = blockIdx.x, tid = threadIdx.x;
  if (bid < 32) {
    int g = bid * 256 + tid;
    int kstep = g >> 8, nt = (g >> 6) & 3, ln = g & 63;
    int n = nt * 16 + (ln & 15);
    int k = kstep * 32 + (ln >> 4) * 8;
    f32x4 a = *(const f32x4*)&Bw[(size_t)n * 1024 + k];
    f32x4 b = *(const f32x4*)&Bw[(size_t)n * 1024 + k + 4];
    *(u16x8*)&BwF[(size_t)g * 8] = __builtin_bit_cast(u16x8, cvt8(a, b));
    return;
  }
  if (bid < 64) {
    int g = (bid - 32) * 256 + tid;
    int dt = g >> 7, kk = (g >> 6) & 1, ln = g & 63;
    int d = dt * 16 + (ln & 15);
    int n = kk * 32 + (ln >> 4) * 8;
    f32x4 a = *(const f32x4*)&Cw[(size_t)d * 64 + n];
    f32x4 b = *(const f32x4*)&Cw[(size_t)d * 64 + n + 4];
    *(u16x8*)&CwF[(size_t)g * 8] = __builtin_bit_cast(u16x8, cvt8(a, b));
    return;
  }
  __shared__ float A[4][64][68];
  __shared__ float AT[64][68];
  __shared__ float Alo[64][36];
  __shared__ float Ahi[32][68];
  __shared__ float vv[64], ww[64];
  const int lane = tid & 63, wq = tid >> 6;
  for (int f = tid; f < 512; f += 256) {
    int r = f >> 3, c = (f & 7) << 2;
    *(f32x4*)&Alo[r][c] = *(const f32x4*)&Al[r * 32 + c];
  }
  for (int f = tid; f < 512; f += 256) {
    int r = f >> 4, c = (f & 15) << 2;
    *(f32x4*)&Ahi[r][c] = *(const f32x4*)&Ah[r * 64 + c];
  }
  if (tid == 0) *norm_out = 0.0f;
  __syncthreads();
  {
    float ar[32];
#pragma unroll
    for (int r = 0; r < 32; r++) ar[r] = Alo[lane][r];
#pragma unroll
    for (int m4 = 0; m4 < 4; m4++) {
      f32x4 s = {0.f, 0.f, 0.f, 0.f};
#pragma unroll
      for (int r = 0; r < 32; r++)
        s += ar[r] * *(const f32x4*)&Ahi[r][wq * 16 + m4 * 4];
      *(f32x4*)&A[0][lane][wq * 16 + m4 * 4] = s;
    }
  }
  __syncthreads();
  for (int f = tid; f < 4096; f += 256) {
    int r = f >> 6, c = f & 63;
    AT[c][r] = A[0][r][c];
  }
  for (int p = 1; p < 4; p++) {
    f32x4 s[4];
#pragma unroll
    for (int m4 = 0; m4 < 4; m4++) s[m4] = f32x4{0.f, 0.f, 0.f, 0.f};
#pragma unroll
    for (int kc = 0; kc < 4; kc++) {
      float ar[16];
#pragma unroll
      for (int r = 0; r < 16; r++) ar[r] = A[p - 1][lane][kc * 16 + r];
#pragma unroll
      for (int r = 0; r < 16; r++)
#pragma unroll
        for (int m4 = 0; m4 < 4; m4++)
          s[m4] += ar[r] * *(const f32x4*)&A[0][kc * 16 + r][wq * 16 + m4 * 4];
    }
#pragma unroll
    for (int m4 = 0; m4 < 4; m4++)
      *(f32x4*)&A[p][lane][wq * 16 + m4 * 4] = s[m4];
    __syncthreads();
  }
#pragma unroll
  for (int i = 0; i < 8; i++) {
    int e = tid + 256 * i;
    int kp = e >> 9, kk = (e >> 8) & 1, nt = (e >> 6) & 3, ln = e & 63;
    int n = nt * 16 + (ln & 15);
    int mc = kk * 32 + (ln >> 4) * 8;
    f32x4 a = *(const f32x4*)&A[kp][n][mc];
    f32x4 b = *(const f32x4*)&A[kp][n][mc + 4];
    *(u16x8*)&akbF[(size_t)e * 8] = __builtin_bit_cast(u16x8, cvt8(a, b));
  }
  if (wq == 0) {
    float v = 1.0f + 0.001f * (float)lane;
    for (int it = 0; it < 8; it++) {
      vv[lane] = v;
      float w0 = 0.f, w1 = 0.f, w2 = 0.f, w3 = 0.f;
#pragma unroll
      for (int m = 0; m < 64; m += 4) {
        w0 += AT[m + 0][lane] * vv[m + 0];
        w1 += AT[m + 1][lane] * vv[m + 1];
        w2 += AT[m + 2][lane] * vv[m + 2];
        w3 += AT[m + 3][lane] * vv[m + 3];
      }
      float w = (w0 + w1) + (w2 + w3);
      ww[lane] = w;
      float z0 = 0.f, z1 = 0.f, z2 = 0.f, z3 = 0.f;
#pragma unroll
      for (int m = 0; m < 64; m += 4) {
        z0 += A[0][m + 0][lane] * ww[m + 0];
        z1 += A[0][m + 1][lane] * ww[m + 1];
        z2 += A[0][m + 2][lane] * ww[m + 2];
        z3 += A[0][m + 3][lane] * ww[m + 3];
      }
      float z = (z0 + z1) + (z2 + z3);
      float ss = z * z;
#pragma unroll
      for (int off = 32; off; off >>= 1) ss += __shfl_xor(ss, off, 64);
      v = z * rsqrtf(ss + 1e-38f);
    }
    vv[lane] = v;
    float w0 = 0.f, w1 = 0.f, w2 = 0.f, w3 = 0.f;
#pragma unroll
    for (int m = 0; m < 64; m += 4) {
      w0 += AT[m + 0][lane] * vv[m + 0];
      w1 += AT[m + 1][lane] * vv[m + 1];
      w2 += AT[m + 2][lane] * vv[m + 2];
      w3 += AT[m + 3][lane] * vv[m + 3];
    }
    float w = (w0 + w1) + (w2 + w3);
    float ss = w * w;
#pragma unroll
    for (int off = 32; off; off >>= 1) ss += __shfl_xor(ss, off, 64);
    if (lane == 0) *spec = sqrtf(ss);
  }
  if (wq == 1) {
    float dm = 0.f;
#pragma unroll
    for (int i = 0; i < 16; i++) dm = fmaxf(dm, fabsf(Dv[lane + i * 64]));
#pragma unroll
    for (int off = 32; off; off >>= 1) dm = fmaxf(dm, __shfl_xor(dm, off, 64));
    if (lane == 0) *dflag = dm;
  }
}

// ---------------------------------------------------------------------------
// G1 (REBUILT, m97-style): wave owns 16 rows x full K. x staged global->LDS
// via global_load_lds width 16, wave-private double buffer, NO barriers.
// Chunk XOR-swizzle (c ^ (r&7)) applied on the GLOBAL source and on the LDS
// read (rule #21) -> ds_read_b128 spreads across all 32 banks.
// Per step: [8 frag loads (L2)] [4 gl_lds stage next] -> compiler auto
// vmcnt(4) waits frags only; top-of-step vmcnt(0) waits the stage.
// ---------------------------------------------------------------------------
__global__ __launch_bounds__(256) void g1_gemm(const float* __restrict__ x,
                                               const unsigned short* __restrict__ BwF,
                                               const float* __restrict__ Bb,
                                               const float* __restrict__ rw,
                                               float* __restrict__ u) {
  __shared__ __align__(16) float xs[4][2][16][16][4];   // 32 KiB
  const int tid = threadIdx.x, lane = tid & 63, wid = tid >> 6;
  const int t0 = blockIdx.x * 64 + wid * 16;
  const int l15 = lane & 15, q = lane >> 4;
  f32x4 acc[4];
#pragma unroll
  for (int nt = 0; nt < 4; nt++) acc[nt] = f32x4{0.f, 0.f, 0.f, 0.f};
  const unsigned short* fb = &BwF[(size_t)lane * 8];

  // prologue: stage step 0 into buf 0
#pragma unroll
  for (int i = 0; i < 4; i++) {
    int ri = i * 4 + q;
    const float* src = &x[(size_t)(t0 + ri) * 1024 + ((l15 ^ (ri & 7)) << 2)];
    __builtin_amdgcn_global_load_lds((gu32*)src, (lu32*)&xs[wid][0][ri][l15][0],
                                     16, 0, 0);
  }

#pragma unroll
  for (int step = 0; step < 16; step++) {
    const int cur = step & 1;
    // wait for current buffer's stage (only this wave's loads are in queue)
    asm volatile("s_waitcnt vmcnt(0)" ::: "memory");
    // weight frags for this step (issued BEFORE next stage)
    bf16x8 fr[2][4];
#pragma unroll
    for (int kk = 0; kk < 2; kk++)
#pragma unroll
      for (int nt = 0; nt < 4; nt++)
        fr[kk][nt] = ld_frag(fb + (size_t)(((step * 2 + kk) * 4 + nt)) * 512);
    // stage next tile into the other buffer
    if (step + 1 < 16) {
#pragma unroll
      for (int i = 0; i < 4; i++) {
        int ri = i * 4 + q;
        const float* src = &x[(size_t)(t0 + ri) * 1024 + (step + 1) * 64 +
                              ((l15 ^ (ri & 7)) << 2)];
        __builtin_amdgcn_global_load_lds((gu32*)src,
                                         (lu32*)&xs[wid][cur ^ 1][ri][l15][0],
                                         16, 0, 0);
      }
    }
    // compute from LDS (swizzled reads)
#pragma unroll
    for (int kk = 0; kk < 2; kk++) {
      const int C0 = kk * 8 + q * 2;
      f32x4 a0 = *(const f32x4*)&xs[wid][cur][l15][C0 ^ (l15 & 7)][0];
      f32x4 a1 = *(const f32x4*)&xs[wid][cur][l15][(C0 + 1) ^ (l15 & 7)][0];
      bf16x8 bop = cvt8(a0, a1);
#pragma unroll
      for (int nt = 0; nt < 4; nt++)
        acc[nt] = mfma16(fr[kk][nt], bop, acc[nt]);
    }
  }

  const int trow = t0 + l15;
  const float rwt = rw[trow];
#pragma unroll
  for (int nt = 0; nt < 4; nt++) {
    int n0 = nt * 16 + q * 4;
    f32x4 bb = *(const f32x4*)&Bb[n0];
    f32x4 o;
#pragma unroll
    for (int j = 0; j < 4; j++) o[j] = (acc[nt][j] + bb[j]) * rwt;
    *(f32x4*)&u[(size_t)trow * 64 + n0] = o;
  }
}

// ---------------------------------------------------------------------------
// K2 — identical to R8.
// ---------------------------------------------------------------------------
__global__ __launch_bounds__(256) void k2_hs(const float* __restrict__ u,
                                             const unsigned short* __restrict__ akbF,
                                             unsigned short* __restrict__ hsbF,
                                             float* __restrict__ norm_out) {
  __shared__ unsigned short hsT[4][16][72];
  const int tid = threadIdx.x, lane = tid & 63, wid = tid >> 6;
  const int tt = blockIdx.x * 4 + wid;
  const int t0 = tt * 16;
  const int bst = t0 & ~4095;
  const int l15 = lane & 15;
  const int q8 = (lane >> 4) * 8;
  const int n4 = (lane >> 4) * 4;
  const int tcol = t0 + l15;
  f32x4 h[4];
#pragma unroll
  for (int nt = 0; nt < 4; nt++) h[nt] = f32x4{0.f, 0.f, 0.f, 0.f};
#pragma unroll
  for (int kp = 1; kp <= 4; kp++) {
    const bool ok = (tcol - kp) >= bst;
    const float* up = &u[(size_t)(tcol - kp) * 64];
#pragma unroll
    for (int kk = 0; kk < 2; kk++) {
      f32x4 xa = {0.f, 0.f, 0.f, 0.f}, xb = {0.f, 0.f, 0.f, 0.f};
      if (ok) {
        xa = *(const f32x4*)(up + kk * 32 + q8);
        xb = *(const f32x4*)(up + kk * 32 + q8 + 4);
      }
      bf16x8 b = cvt8(xa, xb);
#pragma unroll
      for (int nt = 0; nt < 4; nt++) {
        bf16x8 a = ld_frag(&akbF[(size_t)((((kp - 1) * 2 + kk) * 4 + nt) * 64 + lane) * 8]);
        h[nt] = mfma16(a, b, h[nt]);
      }
    }
  }
#pragma unroll
  for (int nt = 0; nt < 4; nt++) {
    f32x4 uid = *(const f32x4*)&u[(size_t)tcol * 64 + nt * 16 + n4];
    h[nt] += uid;
  }
  const bool bend = ((t0 + 15) & 4095) == 4095;
  if (bend) {
    float ss = 0.f;
    if (l15 == 15) {
#pragma unroll
      for (int nt = 0; nt < 4; nt++)
#pragma unroll
        for (int j = 0; j < 4; j++) ss += h[nt][j] * h[nt][j];
    }
    ss += __shfl_xor(ss, 16, 64);
    ss += __shfl_xor(ss, 32, 64);
    if (lane == 15) atomicAdd(norm_out, sqrtf(ss) * 0.125f);
  }
#pragma unroll
  for (int nt = 0; nt < 4; nt++) {
    u16x4 pk;
#pragma unroll
    for (int j = 0; j < 4; j++) pk[j] = bf1(h[nt][j]);
    *(u16x4*)&hsT[wid][l15][nt * 16 + n4] = pk;
  }
#pragma unroll
  for (int kk = 0; kk < 2; kk++) {
    bf16x8 hf = ld_frag(&hsT[wid][l15][kk * 32 + q8]);
    *(u16x8*)&hsbF[((size_t)(tt * 2 + kk) * 64 + lane) * 8] =
        __builtin_bit_cast(u16x8, hf);
  }
}

// ---------------------------------------------------------------------------
// G2 weight-stationary — identical to R8 (measured 24.5us vs 19.5us floor).
// ---------------------------------------------------------------------------
__global__ __launch_bounds__(256, 4) void g2_gemm(const unsigned short* __restrict__ hsbF,
                                                  const unsigned short* __restrict__ CwF,
                                                  const float* __restrict__ Cb,
                                                  const float* __restrict__ Dv,
                                                  const float* __restrict__ x,
                                                  const float* __restrict__ dflag,
                                                  float* __restrict__ out) {
  const int tid = threadIdx.x, lane = tid & 63, wid = tid >> 6;
  const int idx = blockIdx.x * 4 + wid;
  const int dc = idx & 15, tg = idx >> 4;
  const int d0 = dc * 64;
  const int l15 = lane & 15;
  const int n4 = (lane >> 4) * 4;
  const bool hasD = (*dflag != 0.0f);
  bf16x8 cw[4][2];
#pragma unroll
  for (int dt = 0; dt < 4; dt++)
#pragma unroll
    for (int kk = 0; kk < 2; kk++)
      cw[dt][kk] = ld_frag(&CwF[(size_t)((((d0 >> 4) + dt) * 2 + kk) * 64 + lane) * 8]);
  f32x4 cb[4], dd[4];
#pragma unroll
  for (int dt = 0; dt < 4; dt++) {
    cb[dt] = *(const f32x4*)&Cb[d0 + dt * 16 + n4];
    dd[dt] = *(const f32x4*)&Dv[d0 + dt * 16 + n4];
  }
#pragma unroll
  for (int s = 0; s < 4; s++) {
    const int tt = tg * 4 + s;
    bf16x8 hf0 = ld_frag(&hsbF[((size_t)(tt * 2 + 0) * 64 + lane) * 8]);
    bf16x8 hf1 = ld_frag(&hsbF[((size_t)(tt * 2 + 1) * 64 + lane) * 8]);
    f32x4 o[4];
#pragma unroll
    for (int dt = 0; dt < 4; dt++) o[dt] = f32x4{0.f, 0.f, 0.f, 0.f};
#pragma unroll
    for (int dt = 0; dt < 4; dt++) {
      o[dt] = mfma16(cw[dt][0], hf0, o[dt]);
      o[dt] = mfma16(cw[dt][1], hf1, o[dt]);
    }
    const int trow = tt * 16 + l15;
    const size_t xrow = (size_t)trow * 1024;
#pragma unroll
    for (int dt = 0; dt < 4; dt++) {
      int db = d0 + dt * 16 + n4;
      f32x4 v = o[dt] + cb[dt];
      if (hasD) {
        f32x4 xv = *(const f32x4*)&x[xrow + db];
        v += dd[dt] * xv;
      }
      *(f32x4*)&out[xrow + db] = v;
    }
  }
}

extern "C" void kernel_launch(void* const* d_in, const int* in_sizes, int n_in,
                              void* d_out, int out_size, void* d_ws, size_t ws_size,
                              hipStream_t stream) {
  const float* x  = (const float*)d_in[0];
  const float* rw = (const float*)d_in[1];
  const float* Al = (const float*)d_in[2];
  const float* Ah = (const float*)d_in[3];
  const float* Bw = (const float*)d_in[4];
  const float* Bb = (const float*)d_in[5];
  const float* Cw = (const float*)d_in[6];
  const float* Cb = (const float*)d_in[7];
  const float* Dv = (const float*)d_in[8];
  float* out = (float*)d_out;

  char* ws = (char*)d_ws;
  unsigned short* akbF  = (unsigned short*)(ws);                      // 32 KiB
  float*          dflag = (float*)(ws + 32768);                       // 4 B
  unsigned short* BwF   = (unsigned short*)(ws + 65536);              // 128 KiB
  unsigned short* CwF   = (unsigned short*)(ws + 196608);             // 128 KiB
  float*          u     = (float*)(ws + 327680);                      // 8 MiB
  unsigned short* hsbF  = (unsigned short*)(ws + 327680 + 8388608);   // 4 MiB

  float* norm_out = out + (out_size - 2);
  float* spec_out = out + (out_size - 1);

  kprep<<<dim3(65), dim3(256), 0, stream>>>(Bw, Cw, Al, Ah, Dv, BwF, CwF, akbF,
                                            dflag, spec_out, norm_out);
  g1_gemm<<<dim3(512), dim3(256), 0, stream>>>(x, BwF, Bb, rw, u);
  k2_hs<<<dim3(512), dim3(256), 0, stream>>>(u, akbF, hsbF, norm_out);
  g2_gemm<<<dim3(2048), dim3(256), 0, stream>>>(hsbF, CwF, Cb, Dv, x, dflag, out);
}